// Round 1
// baseline (539.028 us; speedup 1.0000x reference)
//
#include <hip/hip_runtime.h>

// LieTransport: semi-Lagrangian advection of h_prev (B,C,H,W,R) by flow field.
// B=4, C=64, H=128, W=128, R=16, all float32.
// Per pixel (b,y,x): sample coord from flow*dt, bilinear blend over all C*R.
// Layout: R innermost (16 floats = 64 B contiguous). 4 lanes per pixel, each
// lane owns one float4 of R and loops over C. Output stores fully coalesced;
// gather loads are 64B-granular dwordx4 (random scatter from flow -> rely on
// L2/L3 for the ~4x bilinear re-read; h_prev (256 MB) ~= L3 size).

constexpr int B = 4, C = 64, H = 128, W = 128, R = 16;

__global__ __launch_bounds__(256) void lie_transport_kernel(
    const float* __restrict__ h_prev,
    const float* __restrict__ flow,
    const float* __restrict__ dt,
    float* __restrict__ out) {
  const int tid = blockIdx.x * 256 + threadIdx.x;   // B*H*W*4 threads total
  const int r4  = (tid & 3) * 4;                     // float4 chunk within R
  const int pix = tid >> 2;                          // b*H*W + y*W + x
  const int x = pix & (W - 1);
  const int y = (pix >> 7) & (H - 1);
  const int b = pix >> 14;

  // ---- per-pixel coordinate math (once, outside channel loop) ----
  const float dtb = dt[b];
  const float* fl = flow + (size_t)b * 2 * H * W;
  const float f0 = fl[y * W + x];
  const float f1 = fl[H * W + y * W + x];

  const float bx = -1.0f + 2.0f * (float)x / (float)(W - 1);
  const float by = -1.0f + 2.0f * (float)y / (float)(H - 1);
  const float gx = bx - f0 * dtb;
  const float gy = by - f1 * dtb;
  float ix = ((gx + 1.0f) * (float)W - 1.0f) * 0.5f;
  float iy = ((gy + 1.0f) * (float)H - 1.0f) * 0.5f;
  ix = fminf(fmaxf(ix, 0.0f), (float)(W - 1));
  iy = fminf(fmaxf(iy, 0.0f), (float)(H - 1));

  const float x0f = floorf(ix);
  const float y0f = floorf(iy);
  const float wx = ix - x0f;
  const float wy = iy - y0f;
  const int x0 = min(max((int)x0f, 0), W - 1);
  const int x1 = min(x0 + 1, W - 1);
  const int y0 = min(max((int)y0f, 0), H - 1);
  const int y1 = min(y0 + 1, H - 1);

  const float w00 = (1.0f - wx) * (1.0f - wy);
  const float w01 = wx * (1.0f - wy);
  const float w10 = (1.0f - wx) * wy;
  const float w11 = wx * wy;

  // ---- channel loop: 4x float4 gather + blend + coalesced float4 store ----
  const size_t chwr = (size_t)H * W * R;             // per-channel stride
  const size_t base = (size_t)b * C * chwr;
  const size_t o00 = ((size_t)(y0 * W + x0)) * R + r4;
  const size_t o01 = ((size_t)(y0 * W + x1)) * R + r4;
  const size_t o10 = ((size_t)(y1 * W + x0)) * R + r4;
  const size_t o11 = ((size_t)(y1 * W + x1)) * R + r4;
  const size_t oou = ((size_t)(y  * W + x )) * R + r4;

#pragma unroll 4
  for (int c = 0; c < C; ++c) {
    const size_t cb = base + (size_t)c * chwr;
    const float4 v00 = *(const float4*)(h_prev + cb + o00);
    const float4 v01 = *(const float4*)(h_prev + cb + o01);
    const float4 v10 = *(const float4*)(h_prev + cb + o10);
    const float4 v11 = *(const float4*)(h_prev + cb + o11);
    float4 r;
    r.x = v00.x * w00 + v01.x * w01 + v10.x * w10 + v11.x * w11;
    r.y = v00.y * w00 + v01.y * w01 + v10.y * w10 + v11.y * w11;
    r.z = v00.z * w00 + v01.z * w01 + v10.z * w10 + v11.z * w11;
    r.w = v00.w * w00 + v01.w * w01 + v10.w * w10 + v11.w * w11;
    *(float4*)(out + cb + oou) = r;
  }
}

extern "C" void kernel_launch(void* const* d_in, const int* in_sizes, int n_in,
                              void* d_out, int out_size, void* d_ws, size_t ws_size,
                              hipStream_t stream) {
  const float* h_prev = (const float*)d_in[0];
  const float* flow   = (const float*)d_in[1];
  const float* dt     = (const float*)d_in[2];
  float* out = (float*)d_out;

  const int total_threads = B * H * W * 4;   // 262144
  const int block = 256;
  const int grid = total_threads / block;    // 1024
  lie_transport_kernel<<<grid, block, 0, stream>>>(h_prev, flow, dt, out);
}